// Round 10
// baseline (628.290 us; speedup 1.0000x reference)
//
#include <hip/hip_runtime.h>
#include <cstdint>
#include <cstddef>

// ---------------------------------------------------------------------------
// Transformer block, MI355X bf16 MFMA implementation.
// R18 = R16 (proven best: BK=64 dbuf + counted vmcnt(8), top GEMM 92.5us,
// MfmaUtil 30.6) + conflict-free LDS layout.
// R17 post-mortem: 48KB 3-ring did NOT give 3 blocks/CU (Occupancy stayed
//   21% — LDS granularity) and BK=32 doubled barriers -> 508us. Reverted.
// R16 residual: SQ_LDS_BANK_CONFLICT 8.4M ~= 15% of wall. af/bfr reads
//   (16 rows @ 64B stride) are 8-way conflicts. With the vmcnt drain gone
//   (counted-vmcnt regime), LDS-read is now on the critical path (m252's
//   gate condition) — the conflict fix should finally pay.
// Fix (rule #21: linear dest + permuted SOURCE + same-permuted READ):
//   each 1KB wave-stage chunk (16 rows x 64B) stored granule-major:
//   u16 off = g*128 + r*8 (was r*32+g*8). Source lanes: srow=lane&15,
//   scol=(lane>>4)*8 (same cache lines -> coalescing unchanged). Frag
//   read: (wm*4+i)*512 + lq*128 + l15*8 — 64 lanes span one contiguous
//   1KB -> zero bank conflicts. No instruction-count change anywhere.
// flash_k (32 q-rows/wave), ln_k, transpose_k, epilogues, grids: R16.
// ---------------------------------------------------------------------------

typedef unsigned short u16;
typedef __attribute__((ext_vector_type(8))) __bf16 bf16x8;   // MFMA A/B frag K=32
typedef __attribute__((ext_vector_type(4))) short s16x4;     // MFMA A/B frag K=16
typedef __attribute__((ext_vector_type(4))) float f32x4;     // MFMA C/D frag

#if defined(__has_builtin)
#if __has_builtin(__builtin_amdgcn_global_load_lds)
#define HAS_GLL 1
#endif
#endif

// attention scale 1/sqrt(64) folded with log2(e) so softmax runs in exp2 domain
#define QSCALE 0.18033688011112042f

__device__ __forceinline__ u16 f2bf(float f) {
  union { float f; unsigned int u; } c; c.f = f;
  unsigned int u = c.u;
  u += 0x7FFFu + ((u >> 16) & 1u);   // round-to-nearest-even
  return (u16)(u >> 16);
}
__device__ __forceinline__ u16 f2bf_fast(float f) {   // round-half-up, 2 insts
  union { float f; unsigned int u; } c; c.f = f;
  return (u16)((c.u + 0x8000u) >> 16);
}

// hardware exp2: one v_exp_f32 (transcendental pipe). libm exp2f is ~30 insts
// without -ffast-math — this was flash's VALU hog (R7 counters).
__device__ __forceinline__ float fexp2(float x) {
#if defined(__HIP_DEVICE_COMPILE__)
#if defined(__has_builtin) && __has_builtin(__builtin_amdgcn_exp2f)
  return __builtin_amdgcn_exp2f(x);
#else
  float r;
  asm("v_exp_f32 %0, %1" : "=v"(r) : "v"(x));
  return r;
#endif
#else
  return x;   // host stub, never executed
#endif
}

// K=16 bf16 MFMA (v_mfma_f32_16x16x16_bf16). Device-only; host sees a stub.
__device__ __forceinline__ f32x4 mfma_pv(s16x4 a, s16x4 b, f32x4 c) {
#if defined(__HIP_DEVICE_COMPILE__)
#if defined(__has_builtin) && __has_builtin(__builtin_amdgcn_mfma_f32_16x16x16bf16_1k)
  return __builtin_amdgcn_mfma_f32_16x16x16bf16_1k(a, b, c, 0, 0, 0);
#else
  f32x4 d;
  asm volatile("v_mfma_f32_16x16x16_bf16 %0, %1, %2, %3"
               : "=v"(d) : "v"(a), "v"(b), "v"(c));
  return d;
#endif
#else
  (void)a; (void)b;
  return c;   // host stub, never executed
#endif
}

// async 16B/lane global->LDS stage; l must be wave-uniform, lane i lands at l+16*i
__device__ __forceinline__ void stage16(const u16* g, u16* l, int lane) {
#ifdef HAS_GLL
  __builtin_amdgcn_global_load_lds(
      (const __attribute__((address_space(1))) uint32_t*)(g),
      (__attribute__((address_space(3))) uint32_t*)(l), 16, 0, 0);
#else
  *(int4*)(l + lane * 8) = *(const int4*)g;
#endif
}

// ---------------- LayerNorm: fp32 [rows][1024] -> bf16 [rows][1024] --------
__global__ __launch_bounds__(256) void ln_k(const float* __restrict__ x,
                                            const float* __restrict__ g,
                                            const float* __restrict__ be,
                                            u16* __restrict__ out) {
  const int row = blockIdx.x;
  const int t = threadIdx.x;
  const float4 v = ((const float4*)(x + (size_t)row * 1024))[t];
  float s = v.x + v.y + v.z + v.w;
  float s2 = v.x * v.x + v.y * v.y + v.z * v.z + v.w * v.w;
#pragma unroll
  for (int off = 32; off > 0; off >>= 1) {
    s += __shfl_down(s, off);
    s2 += __shfl_down(s2, off);
  }
  __shared__ float red[8];
  if ((t & 63) == 0) { red[t >> 6] = s; red[4 + (t >> 6)] = s2; }
  __syncthreads();
  const float ts = red[0] + red[1] + red[2] + red[3];
  const float ts2 = red[4] + red[5] + red[6] + red[7];
  const float mu = ts * (1.0f / 1024.0f);
  const float var = ts2 * (1.0f / 1024.0f) - mu * mu;
  const float rstd = rsqrtf(var + 1e-5f);
  const float4 gv = ((const float4*)g)[t];
  const float4 bv = ((const float4*)be)[t];
  u16* op = out + (size_t)row * 1024 + t * 4;
  op[0] = f2bf((v.x - mu) * rstd * gv.x + bv.x);
  op[1] = f2bf((v.y - mu) * rstd * gv.y + bv.y);
  op[2] = f2bf((v.z - mu) * rstd * gv.z + bv.z);
  op[3] = f2bf((v.w - mu) * rstd * gv.w + bv.w);
}

// ------------- batched transpose fp32 [b][R][C] -> bf16 [b][C][R] ----------
__global__ __launch_bounds__(256) void transpose_k(const float* __restrict__ in,
                                                   u16* __restrict__ out,
                                                   int R, int Cc) {
  __shared__ float tile[32][33];
  const size_t base = (size_t)blockIdx.z * R * Cc;
  const int r0 = blockIdx.x * 32, c0 = blockIdx.y * 32;
  const int tx = threadIdx.x & 31, ty = threadIdx.x >> 5;
  const float* ip = in + base;
  u16* op = out + base;
#pragma unroll
  for (int i = 0; i < 32; i += 8)
    tile[ty + i][tx] = ip[(size_t)(r0 + ty + i) * Cc + c0 + tx];
  __syncthreads();
#pragma unroll
  for (int i = 0; i < 32; i += 8)
    op[(size_t)(c0 + ty + i) * R + r0 + tx] = f2bf(tile[tx][ty + i]);
}

// ---------------- GEMM: C[M][N] = A[M][K] * Bt[N][K]^T, epilogues ----------
// 4 waves (256 thr), 128x128 tile, BK=64 (two sub-tiles), acc 4x4, dbuf.
// Counted-vmcnt (T4): per K-step issue STAGE(t+1) (8 loads/wave), wait
// vmcnt(8) = tile t only; t+1's loads stay in flight across the barrier.
// LDS layout: per 16-row chunk (1KB), granule-major: u16 off within chunk
// = g*128 + r*8 (g = 16B K-granule 0..3, r = row 0..15). Stage source lane
// p = g*16+r -> srow=lane&15, scol=(lane>>4)*8. Frag read af[i]/bfr[j]:
// chunk*512 + lq*128 + l15*8 -> wave spans contiguous 1KB, 0 conflicts.
// MODE 0: scatter to q[B,H,T,64] (pre-scaled), K' frag-order, V' frag-order
// MODE 1: out0(f32) = acc + bias[n] + resid[m][n]      (Wo proj + residual)
// MODE 2: out0(bf16) = relu(acc + bias[n])             (MLP up)
// MODE 3: out0(f32) = acc + bias[n] + resid[m][n]      (MLP down + residual)
template <int MODE>
__global__ __launch_bounds__(256, 2) void gemm_k(
    const u16* __restrict__ A, const u16* __restrict__ Bt,
    const float* __restrict__ bias, const float* __restrict__ resid,
    void* __restrict__ out0, void* __restrict__ out1, void* __restrict__ out2,
    int M, int N, int K) {
  __shared__ u16 As[2][2][128 * 32];   // [buf][kk][chunk*512 + g*128 + r*8]
  __shared__ u16 Bs[2][2][128 * 32];
  const int tid = threadIdx.x;
  const int lane = tid & 63;
  const int w = tid >> 6;
  const int wm = w & 1, wn = w >> 1;        // 2x2 wave grid, 64x64 per wave
  const int l15 = lane & 15, lq = lane >> 4;
  const int m0 = blockIdx.x * 128, n0 = blockIdx.y * 128;
  const int srow = lane & 15;               // granule-major source mapping
  const int scol = (lane >> 4) * 8;

  f32x4 acc[4][4] = {};

  // wave w stages As rows [w*32, w*32+32) and Bs rows [w*32, w*32+32)
  const u16* gA0 = A  + (size_t)(m0 + w * 32 + srow) * K + scol;
  const u16* gA1 = gA0 + (size_t)16 * K;
  const u16* gB0 = Bt + (size_t)(n0 + w * 32 + srow) * K + scol;
  const u16* gB1 = gB0 + (size_t)16 * K;
  const int lofs = (w * 32) * 32;           // = chunk (2w) * 512 u16

  // stage both 32-wide halves of the 64-wide tile at k0 into buffer buf
  auto STAGE = [&](int buf, int k0) {
    stage16(gA0 + k0,      &As[buf][0][lofs], lane);
    stage16(gA1 + k0,      &As[buf][0][lofs + 512], lane);
    stage16(gA0 + k0 + 32, &As[buf][1][lofs], lane);
    stage16(gA1 + k0 + 32, &As[buf][1][lofs + 512], lane);
    stage16(gB0 + k0,      &Bs[buf][0][lofs], lane);
    stage16(gB1 + k0,      &Bs[buf][0][lofs + 512], lane);
    stage16(gB0 + k0 + 32, &Bs[buf][1][lofs], lane);
    stage16(gB1 + k0 + 32, &Bs[buf][1][lofs + 512], lane);
  };

  // prologue: stage tile 0 into buf 0 (8 loads in flight)
  STAGE(0, 0);

  int cur = 0;
  for (int k0 = 0; k0 < K; k0 += 64) {
    if (k0 + 64 < K) {
      STAGE(cur ^ 1, k0 + 64);   // 8 more loads: 16 outstanding
      // wait for the OLDEST 8 (tile t, issued one iteration ago);
      // tile t+1's 8 loads remain in flight across the barrier.
      asm volatile("s_waitcnt vmcnt(8)" ::: "memory");
    } else {
      asm volatile("s_waitcnt vmcnt(0)" ::: "memory");   // tail: drain last tile
    }
    __builtin_amdgcn_s_barrier();        // all waves: tile t fully in LDS
    __builtin_amdgcn_sched_barrier(0);   // pin ds_reads below the wait+barrier
#pragma unroll
    for (int kk = 0; kk < 2; ++kk) {
      bf16x8 af[4], bfr[4];
#pragma unroll
      for (int i = 0; i < 4; ++i)
        af[i] = *(const bf16x8*)&As[cur][kk][(wm * 4 + i) * 512 + lq * 128 + l15 * 8];
#pragma unroll
      for (int j = 0; j < 4; ++j)
        bfr[j] = *(const bf16x8*)&Bs[cur][kk][(wn * 4 + j) * 512 + lq * 128 + l15 * 8];
#pragma unroll
      for (int i = 0; i < 4; ++i)
#pragma unroll
        for (int j = 0; j < 4; ++j)
          acc[i][j] = __builtin_amdgcn_mfma_f32_16x16x32_bf16(af[i], bfr[j], acc[i][j], 0, 0, 0);
    }
    __builtin_amdgcn_sched_barrier(0);   // keep next-iter STAGE below
    __builtin_amdgcn_s_barrier();        // all waves done reading buf (no drain)
    cur ^= 1;
  }

#pragma unroll
  for (int i = 0; i < 4; ++i) {
    const int mbase = m0 + wm * 64 + i * 16 + lq * 4;   // C/D row = lq*4+r
#pragma unroll
    for (int j = 0; j < 4; ++j) {
      const int ncol = n0 + wn * 64 + j * 16 + l15;     // C/D col = l15
#pragma unroll
      for (int r = 0; r < 4; ++r) {
        const float v = acc[i][j][r];
        const int m = mbase + r;
        if (MODE == 0) {
          const int which = ncol >> 10;
          const int hh = (ncol >> 6) & 15;
          const int dd = ncol & 63;
          const int tt = m & 2047;
          const size_t bhb = (size_t)((m >> 11) * 16 + hh) * 131072;
          if (which == 0) {  // q row-major [bh][t][d], pre-scaled
            ((u16*)out0)[bhb + tt * 64 + dd] = f2bf(v * QSCALE);
          } else if (which == 1) {
            // K': bh*131072 + jg*1024 + kk*512 + lane*8 + e
            //   jg=t/16, kk=d/32, lane=((d%32)/8)*16 + t%16, e=d%8
            ((u16*)out1)[bhb + (tt >> 4) * 1024 + (dd >> 5) * 512 +
                         ((((dd & 31) >> 3) * 16 + (tt & 15)) << 3) + (dd & 7)] = f2bf(v);
          } else {
            // V': bh*131072 + dt*32768 + jg*256 + lane*4 + i
            //   dt=d/16, jg=t/16, lane=(d%16) + ((t%16)/4)*16, i=t%4
            ((u16*)out2)[bhb + (dd >> 4) * 32768 + (tt >> 4) * 256 +
                         (((dd & 15) + (((tt >> 2) & 3)) * 16) << 2) + (tt & 3)] = f2bf(v);
          }
        } else if (MODE == 1 || MODE == 3) {
          ((float*)out0)[(size_t)m * N + ncol] =
              v + bias[ncol] + resid[(size_t)m * N + ncol];
        } else {
          const float t2 = v + bias[ncol];
          ((u16*)out0)[(size_t)m * N + ncol] = f2bf(t2 > 0.0f ? t2 : 0.0f);
        }
      }
    }
  }
}

// ---------------- causal flash attention (32 q-rows per wave) --------------
// q (pre-scaled, exp2 domain): [BH][2048][64] bf16 row-major.
// k: K' frag order — subtile t load = kC + t*1024 (+512 for kk=1), 1KB/wave.
// v: V' frag order — (dt,t) load = vC + dt*32768 + t*256, 512B/wave.
// attn out: [B][2048][1024] bf16. Block = (bh, 128 Q rows), 4 waves x 32 rows.
// Each wave owns TWO 16-row S^T fragments (A: rows [q0w,q0w+16),
// B: rows [q0w+16,q0w+32)) and reuses each K/V subtile read for both —
// halves L2 traffic per unit work vs R10 (the measured 19 TB/s L2 wall).
// S^T = K·Q^T: C/D layout of S^T IS the K=16 B-frag layout, so P feeds
// O^T = V^T·P^T with zero cross-lane movement. No max-tracking (scores
// bounded, diagonal guarantees l>=1).
__global__ __launch_bounds__(256, 4) void flash_k(const u16* __restrict__ q,
                                                  const u16* __restrict__ k,
                                                  const u16* __restrict__ vt,
                                                  u16* __restrict__ attn) {
  const int bh = blockIdx.x;                 // XCD affinity: bh%8 (64*qblk%8==0)
  const int qblk = 15 - blockIdx.y;          // longest blocks dispatch first
  const int bb = bh >> 4, hh = bh & 15;
  const int tid = threadIdx.x;
  const int lane = tid & 63, wid = tid >> 6;
  const int l15 = lane & 15, lq = lane >> 4;
  const int q0w = qblk * 128 + wid * 32;     // this wave's Q-row base (32 rows)

  // Q B-frags for fragment A (rows q0w..+15) and B (rows q0w+16..+31)
  const u16* qrowA = q + ((size_t)bh * 2048 + q0w + l15) * 64 + lq * 8;
  const bf16x8 qA0 = *(const bf16x8*)qrowA;
  const bf16x8 qA1 = *(const bf16x8*)(qrowA + 32);
  const u16* qrowB = qrowA + 16 * 64;
  const bf16x8 qB0 = *(const bf16x8*)qrowB;
  const bf16x8 qB1 = *(const bf16x8*)(qrowB + 32);

  // coalesced fragment stream bases (layout unchanged from R8/R10)
  const u16* kC = k + (size_t)bh * 131072 + lane * 8;    // + t*1024 (+512 kk=1)
  const u16* vC = vt + (size_t)bh * 131072 + lane * 4;   // + dt*32768 + t*256

  f32x4 oA[4] = {}, oB[4] = {};   // o[dt]: row = d = lq*4+r (+16*dt), col = l15
  float lA = 0.0f, lB = 0.0f;     // softmax denominator partials per fragment

  const int nt = q0w >> 4;   // subtiles fully unmasked for BOTH fragments

#pragma unroll 2
  for (int t = 0; t < nt; ++t) {
    const int ko = t * 1024, vo = t * 256;
    const bf16x8 ck0 = *(const bf16x8*)(kC + ko);
    const bf16x8 ck1 = *(const bf16x8*)(kC + ko + 512);
    const s16x4 cv0 = *(const s16x4*)(vC + vo);
    const s16x4 cv1 = *(const s16x4*)(vC + vo + 32768);
    const s16x4 cv2 = *(const s16x4*)(vC + vo + 65536);
    const s16x4 cv3 = *(const s16x4*)(vC + vo + 98304);

    f32x4 stA = {}, stB = {};
    __builtin_amdgcn_s_setprio(1);
    stA = __builtin_amdgcn_mfma_f32_16x16x32_bf16(ck0, qA0, stA, 0, 0, 0);
    stA = __builtin_amdgcn_mfma_f32_16x16x32_bf16(ck1, qA1, stA, 0, 0, 0);
    stB = __builtin_amdgcn_mfma_f32_16x16x32_bf16(ck0, qB0, stB, 0, 0, 0);
    stB = __builtin_amdgcn_mfma_f32_16x16x32_bf16(ck1, qB1, stB, 0, 0, 0);
    __builtin_amdgcn_s_setprio(0);

    const float a0 = fexp2(stA[0]), a1 = fexp2(stA[1]);
    const float a2 = fexp2(stA[2]), a3 = fexp2(stA[3]);
    const float b0 = fexp2(stB[0]), b1 = fexp2(stB[1]);
    const float b2 = fexp2(stB[2]), b3 = fexp2(stB[3]);
    lA += (a0 + a1) + (a2 + a3);
    lB += (b0 + b1) + (b2 + b3);
    s16x4 pfA, pfB;
    pfA[0] = (short)f2bf_fast(a0); pfA[1] = (short)f2bf_fast(a1);
    pfA[2] = (short)f2bf_fast(a2); pfA[3] = (short)f2bf_fast(a3);
    pfB[0] = (short)f2bf_fast(b0); pfB[1] = (short)f2bf_fast(b1);
    pfB[2] = (short)f2bf_fast(b2); pfB[3] = (short)f2bf_fast(b3);

    __builtin_amdgcn_s_setprio(1);
    oA[0] = mfma_pv(cv0, pfA, oA[0]);
    oA[1] = mfma_pv(cv1, pfA, oA[1]);
    oA[2] = mfma_pv(cv2, pfA, oA[2]);
    oA[3] = mfma_pv(cv3, pfA, oA[3]);
    oB[0] = mfma_pv(cv0, pfB, oB[0]);
    oB[1] = mfma_pv(cv1, pfB, oB[1]);
    oB[2] = mfma_pv(cv2, pfB, oB[2]);
    oB[3] = mfma_pv(cv3, pfB, oB[3]);
    __builtin_amdgcn_s_setprio(0);
  }

  // ---- subtile nt: diagonal for fragment A, full for fragment B ----
  {
    const int ko = nt * 1024, vo = nt * 256;
    const bf16x8 ck0 = *(const bf16x8*)(kC + ko);
    const bf16x8 ck1 = *(const bf16x8*)(kC + ko + 512);
    const s16x4 cv0 = *(const s16x4*)(vC + vo);
    const s16x4 cv1 = *(const s16x4*)(vC + vo + 32768);
    const s16x4 cv2 = *(const s16x4*)(vC + vo + 65536);
    const s16x4 cv3 = *(const s16x4*)(vC + vo + 98304);

    f32x4 stA = {}, stB = {};
    stA = __builtin_amdgcn_mfma_f32_16x16x32_bf16(ck0, qA0, stA, 0, 0, 0);
    stA = __builtin_amdgcn_mfma_f32_16x16x32_bf16(ck1, qA1, stA, 0, 0, 0);
    stB = __builtin_amdgcn_mfma_f32_16x16x32_bf16(ck0, qB0, stB, 0, 0, 0);
    stB = __builtin_amdgcn_mfma_f32_16x16x32_bf16(ck1, qB1, stB, 0, 0, 0);
#pragma unroll
    for (int r = 0; r < 4; ++r)
      if (lq * 4 + r > l15) stA[r] = -1e30f;   // key row > q row within tile

    const float a0 = fexp2(stA[0]), a1 = fexp2(stA[1]);
    const float a2 = fexp2(stA[2]), a3 = fexp2(stA[3]);
    const float b0 = fexp2(stB[0]), b1 = fexp2(stB[1]);
    const float b2 = fexp2(stB[2]), b3 = fexp2(stB[3]);
    lA += (a0 + a1) + (a2 + a3);
    lB += (b0 + b1) + (b2 + b3);
    s16x4 pfA, pfB;
    pfA[0] = (short)f2bf_fast(a0); pfA[1] = (short)f2bf_fast(a1);
    pfA[2] = (short)f2bf_fast(a2); pfA[3] = (short)f2bf_fast(a3);
    pfB[0] = (short)f2bf_fast(b0); pfB[1] = (short)f2bf_fast(b1);
    pfB[2] = (short)f2bf_fast(b2); pfB[3] = (short)f2bf_fast(b3);

    oA[0] = mfma_pv(cv0, pfA, oA[0]);
    oA[1] = mfma_pv(cv1, pfA, oA[1]);
    oA[2] = mfma_pv(cv2, pfA, oA[2]);
    oA[3] = mfma_pv(cv3, pfA, oA[3]);
    oB[0] = mfma_pv(cv0, pfB, oB[0]);
    oB[1] = mfma_pv(cv1, pfB, oB[1]);
    oB[2] = mfma_pv(cv2, pfB, oB[2]);
    oB[3] = mfma_pv(cv3, pfB, oB[3]);
  }

  // ---- subtile nt+1: diagonal for fragment B only ----
  {
    const int ko = (nt + 1) * 1024, vo = (nt + 1) * 256;
    const bf16x8 ck0 = *(const bf16x8*)(kC + ko);
    const bf16x8 ck1 = *(const bf16x8*)(kC + ko + 512);
    const s16x4 cv0 = *(const s16x4*)(vC + vo);
    const s16x4 cv1 = *(const s16x4*)(vC + vo + 32768);
    const s16x4 cv2 = *(const s16x4*)(vC + vo + 65536);
    const s16x4 cv3 = *(const s16x4*)(vC + vo + 98304);

    f32x4 stB = {};
    stB = __builtin_amdgcn_mfma_f32_16x16x32_bf16(ck0, qB0, stB, 0, 0, 0);
    stB = __builtin_amdgcn_mfma_f32_16x16x32_bf16(ck1, qB1, stB, 0, 0, 0);
#pragma unroll
    for (int r = 0; r < 4; ++r)
      if (lq * 4 + r > l15) stB[r] = -1e30f;

    const float b0 = fexp2(stB[0]), b1 = fexp2(stB[1]);
    const float b2 = fexp2(stB[2]), b3 = fexp2(stB[3]);
    lB += (b0 + b1) + (b2 + b3);
    s16x4 pfB;
    pfB[0] = (short)f2bf_fast(b0); pfB[1] = (short)f2bf_fast(b1);
    pfB[2] = (short)f2bf_fast(b2); pfB[3] = (short)f2bf_fast(b3);

    oB[0] = mfma_pv(cv0, pfB, oB[0]);
    oB[1] = mfma_pv(cv1, pfB, oB[1]);
    oB[2] = mfma_pv(cv2, pfB, oB[2]);
    oB[3] = mfma_pv(cv3, pfB, oB[3]);
  }

  // row-sums: lanes sharing l15 differ in lane bits 4-5
  lA += __shfl_xor(lA, 16);
  lA += __shfl_xor(lA, 32);
  lB += __shfl_xor(lB, 16);
  lB += __shfl_xor(lB, 32);
  const float rlA = 1.0f / lA;
  const float rlB = 1.0f / lB;

  // write: frag A rows q0w+l15, frag B rows q0w+16+l15; d = dt*16 + lq*4 + r
  u16* opA = attn + ((size_t)bb * 2048 + q0w + l15) * 1024 + hh * 64 + lq * 4;
  u16* opB = opA + 16 * 1024;
#pragma unroll
  for (int dt = 0; dt < 4; ++dt) {
    union { s16x4 v; u16 a[4]; } pk;
#pragma unroll
    for (int r = 0; r < 4; ++r) pk.a[r] = f2bf(oA[dt][r] * rlA);
    *(s16x4*)(opA + dt * 16) = pk.v;
#pragma unroll
    for (int r = 0; r < 4; ++r) pk.a[r] = f2bf(oB[dt][r] * rlB);
    *(s16x4*)(opB + dt * 16) = pk.v;
  }
}

// ---------------------------------------------------------------------------
extern "C" void kernel_launch(void* const* d_in, const int* in_sizes, int n_in,
                              void* d_out, int out_size, void* d_ws, size_t ws_size,
                              hipStream_t stream) {
  const float* x   = (const float*)d_in[0];
  const float* Wq  = (const float*)d_in[1];
  const float* Wk  = (const float*)d_in[2];
  const float* Wv  = (const float*)d_in[3];
  const float* Wo  = (const float*)d_in[4];
  const float* bo  = (const float*)d_in[5];
  const float* W1  = (const float*)d_in[6];
  const float* b1  = (const float*)d_in[7];
  const float* W2  = (const float*)d_in[8];
  const float* b2  = (const float*)d_in[9];
  const float* g1  = (const float*)d_in[10];
  const float* be1 = (const float*)d_in[11];
  const float* g2  = (const float*)d_in[12];
  const float* be2 = (const float*)d_in[13];
  float* out = (float*)d_out;

  char* ws = (char*)d_ws;
  u16* Wqkv_t = (u16*)(ws + 0);            //  6 MiB  [3072][1024]
  u16* Wo_t   = (u16*)(ws + 6291456);      //  2 MiB  [1024][1024]
  u16* W1_t   = (u16*)(ws + 8388608);      //  8 MiB  [4096][1024]
  u16* W2_t   = (u16*)(ws + 16777216);     //  8 MiB  [1024][4096]
  u16* hbuf   = (u16*)(ws + 25165824);     // 16 MiB  [8192][1024] (LN out, reused)
  float* x2   = (float*)(ws + 41943040);   // 32 MiB  [8192][1024] f32 mid residual
  u16* vtb    = (u16*)(ws + 41943040);     // 16 MiB  V' frag order, overlaps x2:
                                           //   vtb dead before gemm<1> writes x2
  u16* qb     = (u16*)(ws + 75497472);     // 16 MiB  [64][2048][64]
  u16* kb     = (u16*)(ws + 92274688);     // 16 MiB  K' frag order
  u16* attnb  = (u16*)(ws + 109051904);    // 16 MiB  [8192][1024]
  u16* a1     = (u16*)(ws + 75497472);     // 64 MiB  [8192][4096], reuses qb/kb/attnb

  dim3 blk(256);

  // weights -> bf16, transposed to [N][K]
  transpose_k<<<dim3(32, 2, 16),  blk, 0, stream>>>(Wq, Wqkv_t,            1024, 64);
  transpose_k<<<dim3(32, 2, 16),  blk, 0, stream>>>(Wk, Wqkv_t + 1048576,  1024, 64);
  transpose_k<<<dim3(32, 2, 16),  blk, 0, stream>>>(Wv, Wqkv_t + 2097152,  1024, 64);
  transpose_k<<<dim3(32, 32, 1),  blk, 0, stream>>>(Wo, Wo_t,              1024, 1024);
  transpose_k<<<dim3(32, 128, 1), blk, 0, stream>>>(W1, W1_t,              1024, 4096);
  transpose_k<<<dim3(128, 32, 1), blk, 0, stream>>>(W2, W2_t,              4096, 1024);

  // LN1
  ln_k<<<8192, blk, 0, stream>>>(x, g1, be1, hbuf);
  // QKV projection with fragment-order scatter epilogue (q pre-scaled)
  gemm_k<0><<<dim3(64, 24), blk, 0, stream>>>(hbuf, Wqkv_t, nullptr, nullptr,
                                              qb, kb, vtb, 8192, 3072, 1024);
  // causal flash attention (32 q-rows per wave, 128 per block)
  flash_k<<<dim3(64, 16), blk, 0, stream>>>(qb, kb, vtb, attnb);
  // output projection + bias + residual -> x2 (f32; overwrites dead vtb)
  gemm_k<1><<<dim3(64, 8), blk, 0, stream>>>(attnb, Wo_t, bo, x,
                                             x2, nullptr, nullptr, 8192, 1024, 1024);
  // LN2
  ln_k<<<8192, blk, 0, stream>>>(x2, g2, be2, hbuf);
  // MLP up + relu
  gemm_k<2><<<dim3(64, 32), blk, 0, stream>>>(hbuf, W1_t, b1, nullptr,
                                              a1, nullptr, nullptr, 8192, 4096, 1024);
  // MLP down + bias + residual -> out (f32)
  gemm_k<3><<<dim3(64, 8), blk, 0, stream>>>(a1, W2_t, b2, x2,
                                             out, nullptr, nullptr, 8192, 1024, 4096);
}

// Round 11
// 483.347 us; speedup vs baseline: 1.2999x; 1.2999x over previous
//
#include <hip/hip_runtime.h>
#include <cstdint>
#include <cstddef>

// ---------------------------------------------------------------------------
// Transformer block, MI355X bf16 MFMA implementation.
// R19 = R16 (proven best GEMM: BK=64 dbuf + counted vmcnt(8), 92.5us,
// MfmaUtil 30.6) + coalescing-PRESERVING LDS bank-conflict fix.
// R18 post-mortem: granule-major layout zeroed conflicts but srow=lane&15
//   scattered consecutive lanes K*2 bytes apart -> staging decohered into
//   64x16B requests (4x transactions), 92.5 -> 143us. Lesson: the source
//   permutation must stay WITHIN each contiguous 64B segment.
// Fix (rule #21, m173-style pre-swizzled source): keep srow=lane>>2 (each
//   4-lane group still covers one contiguous 64B row segment -> identical
//   transactions to R16); XOR only the granule within the segment:
//   scol = ((lane&3) ^ ((lane>>3)&3))*16B. LDS slot (row,s) holds granule
//   s ^ ((row>>1)&3); frag read uses (lq ^ ((l15>>1)&3))*16B.
//   Quarter-wave bank slots: R16 = 2 slots/16 lanes (8-way); now 8 slots
//   x 2 lanes = 2-way = free (m136). Involution verified.
// flash_k (32 q-rows/wave), ln_k, transpose_k, epilogues, grids: R16.
// ---------------------------------------------------------------------------

typedef unsigned short u16;
typedef __attribute__((ext_vector_type(8))) __bf16 bf16x8;   // MFMA A/B frag K=32
typedef __attribute__((ext_vector_type(4))) short s16x4;     // MFMA A/B frag K=16
typedef __attribute__((ext_vector_type(4))) float f32x4;     // MFMA C/D frag

#if defined(__has_builtin)
#if __has_builtin(__builtin_amdgcn_global_load_lds)
#define HAS_GLL 1
#endif
#endif

// attention scale 1/sqrt(64) folded with log2(e) so softmax runs in exp2 domain
#define QSCALE 0.18033688011112042f

__device__ __forceinline__ u16 f2bf(float f) {
  union { float f; unsigned int u; } c; c.f = f;
  unsigned int u = c.u;
  u += 0x7FFFu + ((u >> 16) & 1u);   // round-to-nearest-even
  return (u16)(u >> 16);
}
__device__ __forceinline__ u16 f2bf_fast(float f) {   // round-half-up, 2 insts
  union { float f; unsigned int u; } c; c.f = f;
  return (u16)((c.u + 0x8000u) >> 16);
}

// hardware exp2: one v_exp_f32 (transcendental pipe). libm exp2f is ~30 insts
// without -ffast-math — this was flash's VALU hog (R7 counters).
__device__ __forceinline__ float fexp2(float x) {
#if defined(__HIP_DEVICE_COMPILE__)
#if defined(__has_builtin) && __has_builtin(__builtin_amdgcn_exp2f)
  return __builtin_amdgcn_exp2f(x);
#else
  float r;
  asm("v_exp_f32 %0, %1" : "=v"(r) : "v"(x));
  return r;
#endif
#else
  return x;   // host stub, never executed
#endif
}

// K=16 bf16 MFMA (v_mfma_f32_16x16x16_bf16). Device-only; host sees a stub.
__device__ __forceinline__ f32x4 mfma_pv(s16x4 a, s16x4 b, f32x4 c) {
#if defined(__HIP_DEVICE_COMPILE__)
#if defined(__has_builtin) && __has_builtin(__builtin_amdgcn_mfma_f32_16x16x16bf16_1k)
  return __builtin_amdgcn_mfma_f32_16x16x16bf16_1k(a, b, c, 0, 0, 0);
#else
  f32x4 d;
  asm volatile("v_mfma_f32_16x16x16_bf16 %0, %1, %2, %3"
               : "=v"(d) : "v"(a), "v"(b), "v"(c));
  return d;
#endif
#else
  (void)a; (void)b;
  return c;   // host stub, never executed
#endif
}

// async 16B/lane global->LDS stage; l must be wave-uniform, lane i lands at l+16*i
__device__ __forceinline__ void stage16(const u16* g, u16* l, int lane) {
#ifdef HAS_GLL
  __builtin_amdgcn_global_load_lds(
      (const __attribute__((address_space(1))) uint32_t*)(g),
      (__attribute__((address_space(3))) uint32_t*)(l), 16, 0, 0);
#else
  *(int4*)(l + lane * 8) = *(const int4*)g;
#endif
}

// ---------------- LayerNorm: fp32 [rows][1024] -> bf16 [rows][1024] --------
__global__ __launch_bounds__(256) void ln_k(const float* __restrict__ x,
                                            const float* __restrict__ g,
                                            const float* __restrict__ be,
                                            u16* __restrict__ out) {
  const int row = blockIdx.x;
  const int t = threadIdx.x;
  const float4 v = ((const float4*)(x + (size_t)row * 1024))[t];
  float s = v.x + v.y + v.z + v.w;
  float s2 = v.x * v.x + v.y * v.y + v.z * v.z + v.w * v.w;
#pragma unroll
  for (int off = 32; off > 0; off >>= 1) {
    s += __shfl_down(s, off);
    s2 += __shfl_down(s2, off);
  }
  __shared__ float red[8];
  if ((t & 63) == 0) { red[t >> 6] = s; red[4 + (t >> 6)] = s2; }
  __syncthreads();
  const float ts = red[0] + red[1] + red[2] + red[3];
  const float ts2 = red[4] + red[5] + red[6] + red[7];
  const float mu = ts * (1.0f / 1024.0f);
  const float var = ts2 * (1.0f / 1024.0f) - mu * mu;
  const float rstd = rsqrtf(var + 1e-5f);
  const float4 gv = ((const float4*)g)[t];
  const float4 bv = ((const float4*)be)[t];
  u16* op = out + (size_t)row * 1024 + t * 4;
  op[0] = f2bf((v.x - mu) * rstd * gv.x + bv.x);
  op[1] = f2bf((v.y - mu) * rstd * gv.y + bv.y);
  op[2] = f2bf((v.z - mu) * rstd * gv.z + bv.z);
  op[3] = f2bf((v.w - mu) * rstd * gv.w + bv.w);
}

// ------------- batched transpose fp32 [b][R][C] -> bf16 [b][C][R] ----------
__global__ __launch_bounds__(256) void transpose_k(const float* __restrict__ in,
                                                   u16* __restrict__ out,
                                                   int R, int Cc) {
  __shared__ float tile[32][33];
  const size_t base = (size_t)blockIdx.z * R * Cc;
  const int r0 = blockIdx.x * 32, c0 = blockIdx.y * 32;
  const int tx = threadIdx.x & 31, ty = threadIdx.x >> 5;
  const float* ip = in + base;
  u16* op = out + base;
#pragma unroll
  for (int i = 0; i < 32; i += 8)
    tile[ty + i][tx] = ip[(size_t)(r0 + ty + i) * Cc + c0 + tx];
  __syncthreads();
#pragma unroll
  for (int i = 0; i < 32; i += 8)
    op[(size_t)(c0 + ty + i) * R + r0 + tx] = f2bf(tile[tx][ty + i]);
}

// ---------------- GEMM: C[M][N] = A[M][K] * Bt[N][K]^T, epilogues ----------
// 4 waves (256 thr), 128x128 tile, BK=64 (two sub-tiles), acc 4x4, dbuf.
// Counted-vmcnt (T4): per K-step issue STAGE(t+1) (8 loads/wave), wait
// vmcnt(8) = tile t only; t+1's loads stay in flight across the barrier.
// LDS bank fix: within each 16-row/64B-segment chunk, granule XOR-swizzled:
// source lane p loads granule (p&3)^((p>>3)&3) of row p>>2 (same 64B
// segment per 4-lane group -> coalescing identical to R16); frag read at
// granule (lq ^ ((l15>>1)&3)) -> quarter-wave spreads over 8 bank-slots
// x 2 lanes = 2-way (free) instead of R16's 8-way.
// MODE 0: scatter to q[B,H,T,64] (pre-scaled), K' frag-order, V' frag-order
// MODE 1: out0(f32) = acc + bias[n] + resid[m][n]      (Wo proj + residual)
// MODE 2: out0(bf16) = relu(acc + bias[n])             (MLP up)
// MODE 3: out0(f32) = acc + bias[n] + resid[m][n]      (MLP down + residual)
template <int MODE>
__global__ __launch_bounds__(256, 2) void gemm_k(
    const u16* __restrict__ A, const u16* __restrict__ Bt,
    const float* __restrict__ bias, const float* __restrict__ resid,
    void* __restrict__ out0, void* __restrict__ out1, void* __restrict__ out2,
    int M, int N, int K) {
  __shared__ u16 As[2][2][128 * 32];   // [buf][kk][row*32 + swz_granule*8]
  __shared__ u16 Bs[2][2][128 * 32];
  const int tid = threadIdx.x;
  const int lane = tid & 63;
  const int w = tid >> 6;
  const int wm = w & 1, wn = w >> 1;        // 2x2 wave grid, 64x64 per wave
  const int l15 = lane & 15, lq = lane >> 4;
  const int m0 = blockIdx.x * 128, n0 = blockIdx.y * 128;
  const int srow = lane >> 2;                       // same rows as R16
  const int scol = ((lane & 3) ^ ((lane >> 3) & 3)) * 8;  // XOR within 64B seg
  const int rsw = (lq ^ ((l15 >> 1) & 3)) * 8;      // read-side granule swizzle

  f32x4 acc[4][4] = {};

  // wave w stages As rows [w*32, w*32+32) and Bs rows [w*32, w*32+32)
  const u16* gA0 = A  + (size_t)(m0 + w * 32 + srow) * K + scol;
  const u16* gA1 = gA0 + (size_t)16 * K;
  const u16* gB0 = Bt + (size_t)(n0 + w * 32 + srow) * K + scol;
  const u16* gB1 = gB0 + (size_t)16 * K;
  const int lofs = (w * 32) * 32;           // wave's row block within a sub-tile

  // stage both 32-wide halves of the 64-wide tile at k0 into buffer buf
  auto STAGE = [&](int buf, int k0) {
    stage16(gA0 + k0,      &As[buf][0][lofs], lane);
    stage16(gA1 + k0,      &As[buf][0][lofs + 512], lane);
    stage16(gA0 + k0 + 32, &As[buf][1][lofs], lane);
    stage16(gA1 + k0 + 32, &As[buf][1][lofs + 512], lane);
    stage16(gB0 + k0,      &Bs[buf][0][lofs], lane);
    stage16(gB1 + k0,      &Bs[buf][0][lofs + 512], lane);
    stage16(gB0 + k0 + 32, &Bs[buf][1][lofs], lane);
    stage16(gB1 + k0 + 32, &Bs[buf][1][lofs + 512], lane);
  };

  // prologue: stage tile 0 into buf 0 (8 loads in flight)
  STAGE(0, 0);

  int cur = 0;
  for (int k0 = 0; k0 < K; k0 += 64) {
    if (k0 + 64 < K) {
      STAGE(cur ^ 1, k0 + 64);   // 8 more loads: 16 outstanding
      // wait for the OLDEST 8 (tile t, issued one iteration ago);
      // tile t+1's 8 loads remain in flight across the barrier.
      asm volatile("s_waitcnt vmcnt(8)" ::: "memory");
    } else {
      asm volatile("s_waitcnt vmcnt(0)" ::: "memory");   // tail: drain last tile
    }
    __builtin_amdgcn_s_barrier();        // all waves: tile t fully in LDS
    __builtin_amdgcn_sched_barrier(0);   // pin ds_reads below the wait+barrier
#pragma unroll
    for (int kk = 0; kk < 2; ++kk) {
      bf16x8 af[4], bfr[4];
#pragma unroll
      for (int i = 0; i < 4; ++i)
        af[i] = *(const bf16x8*)&As[cur][kk][(wm * 64 + i * 16 + l15) * 32 + rsw];
#pragma unroll
      for (int j = 0; j < 4; ++j)
        bfr[j] = *(const bf16x8*)&Bs[cur][kk][(wn * 64 + j * 16 + l15) * 32 + rsw];
#pragma unroll
      for (int i = 0; i < 4; ++i)
#pragma unroll
        for (int j = 0; j < 4; ++j)
          acc[i][j] = __builtin_amdgcn_mfma_f32_16x16x32_bf16(af[i], bfr[j], acc[i][j], 0, 0, 0);
    }
    __builtin_amdgcn_sched_barrier(0);   // keep next-iter STAGE below
    __builtin_amdgcn_s_barrier();        // all waves done reading buf (no drain)
    cur ^= 1;
  }

#pragma unroll
  for (int i = 0; i < 4; ++i) {
    const int mbase = m0 + wm * 64 + i * 16 + lq * 4;   // C/D row = lq*4+r
#pragma unroll
    for (int j = 0; j < 4; ++j) {
      const int ncol = n0 + wn * 64 + j * 16 + l15;     // C/D col = l15
#pragma unroll
      for (int r = 0; r < 4; ++r) {
        const float v = acc[i][j][r];
        const int m = mbase + r;
        if (MODE == 0) {
          const int which = ncol >> 10;
          const int hh = (ncol >> 6) & 15;
          const int dd = ncol & 63;
          const int tt = m & 2047;
          const size_t bhb = (size_t)((m >> 11) * 16 + hh) * 131072;
          if (which == 0) {  // q row-major [bh][t][d], pre-scaled
            ((u16*)out0)[bhb + tt * 64 + dd] = f2bf(v * QSCALE);
          } else if (which == 1) {
            // K': bh*131072 + jg*1024 + kk*512 + lane*8 + e
            //   jg=t/16, kk=d/32, lane=((d%32)/8)*16 + t%16, e=d%8
            ((u16*)out1)[bhb + (tt >> 4) * 1024 + (dd >> 5) * 512 +
                         ((((dd & 31) >> 3) * 16 + (tt & 15)) << 3) + (dd & 7)] = f2bf(v);
          } else {
            // V': bh*131072 + dt*32768 + jg*256 + lane*4 + i
            //   dt=d/16, jg=t/16, lane=(d%16) + ((t%16)/4)*16, i=t%4
            ((u16*)out2)[bhb + (dd >> 4) * 32768 + (tt >> 4) * 256 +
                         (((dd & 15) + (((tt >> 2) & 3)) * 16) << 2) + (tt & 3)] = f2bf(v);
          }
        } else if (MODE == 1 || MODE == 3) {
          ((float*)out0)[(size_t)m * N + ncol] =
              v + bias[ncol] + resid[(size_t)m * N + ncol];
        } else {
          const float t2 = v + bias[ncol];
          ((u16*)out0)[(size_t)m * N + ncol] = f2bf(t2 > 0.0f ? t2 : 0.0f);
        }
      }
    }
  }
}

// ---------------- causal flash attention (32 q-rows per wave) --------------
// q (pre-scaled, exp2 domain): [BH][2048][64] bf16 row-major.
// k: K' frag order — subtile t load = kC + t*1024 (+512 for kk=1), 1KB/wave.
// v: V' frag order — (dt,t) load = vC + dt*32768 + t*256, 512B/wave.
// attn out: [B][2048][1024] bf16. Block = (bh, 128 Q rows), 4 waves x 32 rows.
// Each wave owns TWO 16-row S^T fragments (A: rows [q0w,q0w+16),
// B: rows [q0w+16,q0w+32)) and reuses each K/V subtile read for both —
// halves L2 traffic per unit work vs R10 (the measured 19 TB/s L2 wall).
// S^T = K·Q^T: C/D layout of S^T IS the K=16 B-frag layout, so P feeds
// O^T = V^T·P^T with zero cross-lane movement. No max-tracking (scores
// bounded, diagonal guarantees l>=1).
__global__ __launch_bounds__(256, 4) void flash_k(const u16* __restrict__ q,
                                                  const u16* __restrict__ k,
                                                  const u16* __restrict__ vt,
                                                  u16* __restrict__ attn) {
  const int bh = blockIdx.x;                 // XCD affinity: bh%8 (64*qblk%8==0)
  const int qblk = 15 - blockIdx.y;          // longest blocks dispatch first
  const int bb = bh >> 4, hh = bh & 15;
  const int tid = threadIdx.x;
  const int lane = tid & 63, wid = tid >> 6;
  const int l15 = lane & 15, lq = lane >> 4;
  const int q0w = qblk * 128 + wid * 32;     // this wave's Q-row base (32 rows)

  // Q B-frags for fragment A (rows q0w..+15) and B (rows q0w+16..+31)
  const u16* qrowA = q + ((size_t)bh * 2048 + q0w + l15) * 64 + lq * 8;
  const bf16x8 qA0 = *(const bf16x8*)qrowA;
  const bf16x8 qA1 = *(const bf16x8*)(qrowA + 32);
  const u16* qrowB = qrowA + 16 * 64;
  const bf16x8 qB0 = *(const bf16x8*)qrowB;
  const bf16x8 qB1 = *(const bf16x8*)(qrowB + 32);

  // coalesced fragment stream bases (layout unchanged from R8/R10)
  const u16* kC = k + (size_t)bh * 131072 + lane * 8;    // + t*1024 (+512 kk=1)
  const u16* vC = vt + (size_t)bh * 131072 + lane * 4;   // + dt*32768 + t*256

  f32x4 oA[4] = {}, oB[4] = {};   // o[dt]: row = d = lq*4+r (+16*dt), col = l15
  float lA = 0.0f, lB = 0.0f;     // softmax denominator partials per fragment

  const int nt = q0w >> 4;   // subtiles fully unmasked for BOTH fragments

#pragma unroll 2
  for (int t = 0; t < nt; ++t) {
    const int ko = t * 1024, vo = t * 256;
    const bf16x8 ck0 = *(const bf16x8*)(kC + ko);
    const bf16x8 ck1 = *(const bf16x8*)(kC + ko + 512);
    const s16x4 cv0 = *(const s16x4*)(vC + vo);
    const s16x4 cv1 = *(const s16x4*)(vC + vo + 32768);
    const s16x4 cv2 = *(const s16x4*)(vC + vo + 65536);
    const s16x4 cv3 = *(const s16x4*)(vC + vo + 98304);

    f32x4 stA = {}, stB = {};
    __builtin_amdgcn_s_setprio(1);
    stA = __builtin_amdgcn_mfma_f32_16x16x32_bf16(ck0, qA0, stA, 0, 0, 0);
    stA = __builtin_amdgcn_mfma_f32_16x16x32_bf16(ck1, qA1, stA, 0, 0, 0);
    stB = __builtin_amdgcn_mfma_f32_16x16x32_bf16(ck0, qB0, stB, 0, 0, 0);
    stB = __builtin_amdgcn_mfma_f32_16x16x32_bf16(ck1, qB1, stB, 0, 0, 0);
    __builtin_amdgcn_s_setprio(0);

    const float a0 = fexp2(stA[0]), a1 = fexp2(stA[1]);
    const float a2 = fexp2(stA[2]), a3 = fexp2(stA[3]);
    const float b0 = fexp2(stB[0]), b1 = fexp2(stB[1]);
    const float b2 = fexp2(stB[2]), b3 = fexp2(stB[3]);
    lA += (a0 + a1) + (a2 + a3);
    lB += (b0 + b1) + (b2 + b3);
    s16x4 pfA, pfB;
    pfA[0] = (short)f2bf_fast(a0); pfA[1] = (short)f2bf_fast(a1);
    pfA[2] = (short)f2bf_fast(a2); pfA[3] = (short)f2bf_fast(a3);
    pfB[0] = (short)f2bf_fast(b0); pfB[1] = (short)f2bf_fast(b1);
    pfB[2] = (short)f2bf_fast(b2); pfB[3] = (short)f2bf_fast(b3);

    __builtin_amdgcn_s_setprio(1);
    oA[0] = mfma_pv(cv0, pfA, oA[0]);
    oA[1] = mfma_pv(cv1, pfA, oA[1]);
    oA[2] = mfma_pv(cv2, pfA, oA[2]);
    oA[3] = mfma_pv(cv3, pfA, oA[3]);
    oB[0] = mfma_pv(cv0, pfB, oB[0]);
    oB[1] = mfma_pv(cv1, pfB, oB[1]);
    oB[2] = mfma_pv(cv2, pfB, oB[2]);
    oB[3] = mfma_pv(cv3, pfB, oB[3]);
    __builtin_amdgcn_s_setprio(0);
  }

  // ---- subtile nt: diagonal for fragment A, full for fragment B ----
  {
    const int ko = nt * 1024, vo = nt * 256;
    const bf16x8 ck0 = *(const bf16x8*)(kC + ko);
    const bf16x8 ck1 = *(const bf16x8*)(kC + ko + 512);
    const s16x4 cv0 = *(const s16x4*)(vC + vo);
    const s16x4 cv1 = *(const s16x4*)(vC + vo + 32768);
    const s16x4 cv2 = *(const s16x4*)(vC + vo + 65536);
    const s16x4 cv3 = *(const s16x4*)(vC + vo + 98304);

    f32x4 stA = {}, stB = {};
    stA = __builtin_amdgcn_mfma_f32_16x16x32_bf16(ck0, qA0, stA, 0, 0, 0);
    stA = __builtin_amdgcn_mfma_f32_16x16x32_bf16(ck1, qA1, stA, 0, 0, 0);
    stB = __builtin_amdgcn_mfma_f32_16x16x32_bf16(ck0, qB0, stB, 0, 0, 0);
    stB = __builtin_amdgcn_mfma_f32_16x16x32_bf16(ck1, qB1, stB, 0, 0, 0);
#pragma unroll
    for (int r = 0; r < 4; ++r)
      if (lq * 4 + r > l15) stA[r] = -1e30f;   // key row > q row within tile

    const float a0 = fexp2(stA[0]), a1 = fexp2(stA[1]);
    const float a2 = fexp2(stA[2]), a3 = fexp2(stA[3]);
    const float b0 = fexp2(stB[0]), b1 = fexp2(stB[1]);
    const float b2 = fexp2(stB[2]), b3 = fexp2(stB[3]);
    lA += (a0 + a1) + (a2 + a3);
    lB += (b0 + b1) + (b2 + b3);
    s16x4 pfA, pfB;
    pfA[0] = (short)f2bf_fast(a0); pfA[1] = (short)f2bf_fast(a1);
    pfA[2] = (short)f2bf_fast(a2); pfA[3] = (short)f2bf_fast(a3);
    pfB[0] = (short)f2bf_fast(b0); pfB[1] = (short)f2bf_fast(b1);
    pfB[2] = (short)f2bf_fast(b2); pfB[3] = (short)f2bf_fast(b3);

    oA[0] = mfma_pv(cv0, pfA, oA[0]);
    oA[1] = mfma_pv(cv1, pfA, oA[1]);
    oA[2] = mfma_pv(cv2, pfA, oA[2]);
    oA[3] = mfma_pv(cv3, pfA, oA[3]);
    oB[0] = mfma_pv(cv0, pfB, oB[0]);
    oB[1] = mfma_pv(cv1, pfB, oB[1]);
    oB[2] = mfma_pv(cv2, pfB, oB[2]);
    oB[3] = mfma_pv(cv3, pfB, oB[3]);
  }

  // ---- subtile nt+1: diagonal for fragment B only ----
  {
    const int ko = (nt + 1) * 1024, vo = (nt + 1) * 256;
    const bf16x8 ck0 = *(const bf16x8*)(kC + ko);
    const bf16x8 ck1 = *(const bf16x8*)(kC + ko + 512);
    const s16x4 cv0 = *(const s16x4*)(vC + vo);
    const s16x4 cv1 = *(const s16x4*)(vC + vo + 32768);
    const s16x4 cv2 = *(const s16x4*)(vC + vo + 65536);
    const s16x4 cv3 = *(const s16x4*)(vC + vo + 98304);

    f32x4 stB = {};
    stB = __builtin_amdgcn_mfma_f32_16x16x32_bf16(ck0, qB0, stB, 0, 0, 0);
    stB = __builtin_amdgcn_mfma_f32_16x16x32_bf16(ck1, qB1, stB, 0, 0, 0);
#pragma unroll
    for (int r = 0; r < 4; ++r)
      if (lq * 4 + r > l15) stB[r] = -1e30f;

    const float b0 = fexp2(stB[0]), b1 = fexp2(stB[1]);
    const float b2 = fexp2(stB[2]), b3 = fexp2(stB[3]);
    lB += (b0 + b1) + (b2 + b3);
    s16x4 pfB;
    pfB[0] = (short)f2bf_fast(b0); pfB[1] = (short)f2bf_fast(b1);
    pfB[2] = (short)f2bf_fast(b2); pfB[3] = (short)f2bf_fast(b3);

    oB[0] = mfma_pv(cv0, pfB, oB[0]);
    oB[1] = mfma_pv(cv1, pfB, oB[1]);
    oB[2] = mfma_pv(cv2, pfB, oB[2]);
    oB[3] = mfma_pv(cv3, pfB, oB[3]);
  }

  // row-sums: lanes sharing l15 differ in lane bits 4-5
  lA += __shfl_xor(lA, 16);
  lA += __shfl_xor(lA, 32);
  lB += __shfl_xor(lB, 16);
  lB += __shfl_xor(lB, 32);
  const float rlA = 1.0f / lA;
  const float rlB = 1.0f / lB;

  // write: frag A rows q0w+l15, frag B rows q0w+16+l15; d = dt*16 + lq*4 + r
  u16* opA = attn + ((size_t)bb * 2048 + q0w + l15) * 1024 + hh * 64 + lq * 4;
  u16* opB = opA + 16 * 1024;
#pragma unroll
  for (int dt = 0; dt < 4; ++dt) {
    union { s16x4 v; u16 a[4]; } pk;
#pragma unroll
    for (int r = 0; r < 4; ++r) pk.a[r] = f2bf(oA[dt][r] * rlA);
    *(s16x4*)(opA + dt * 16) = pk.v;
#pragma unroll
    for (int r = 0; r < 4; ++r) pk.a[r] = f2bf(oB[dt][r] * rlB);
    *(s16x4*)(opB + dt * 16) = pk.v;
  }
}

// ---------------------------------------------------------------------------
extern "C" void kernel_launch(void* const* d_in, const int* in_sizes, int n_in,
                              void* d_out, int out_size, void* d_ws, size_t ws_size,
                              hipStream_t stream) {
  const float* x   = (const float*)d_in[0];
  const float* Wq  = (const float*)d_in[1];
  const float* Wk  = (const float*)d_in[2];
  const float* Wv  = (const float*)d_in[3];
  const float* Wo  = (const float*)d_in[4];
  const float* bo  = (const float*)d_in[5];
  const float* W1  = (const float*)d_in[6];
  const float* b1  = (const float*)d_in[7];
  const float* W2  = (const float*)d_in[8];
  const float* b2  = (const float*)d_in[9];
  const float* g1  = (const float*)d_in[10];
  const float* be1 = (const float*)d_in[11];
  const float* g2  = (const float*)d_in[12];
  const float* be2 = (const float*)d_in[13];
  float* out = (float*)d_out;

  char* ws = (char*)d_ws;
  u16* Wqkv_t = (u16*)(ws + 0);            //  6 MiB  [3072][1024]
  u16* Wo_t   = (u16*)(ws + 6291456);      //  2 MiB  [1024][1024]
  u16* W1_t   = (u16*)(ws + 8388608);      //  8 MiB  [4096][1024]
  u16* W2_t   = (u16*)(ws + 16777216);     //  8 MiB  [1024][4096]
  u16* hbuf   = (u16*)(ws + 25165824);     // 16 MiB  [8192][1024] (LN out, reused)
  float* x2   = (float*)(ws + 41943040);   // 32 MiB  [8192][1024] f32 mid residual
  u16* vtb    = (u16*)(ws + 41943040);     // 16 MiB  V' frag order, overlaps x2:
                                           //   vtb dead before gemm<1> writes x2
  u16* qb     = (u16*)(ws + 75497472);     // 16 MiB  [64][2048][64]
  u16* kb     = (u16*)(ws + 92274688);     // 16 MiB  K' frag order
  u16* attnb  = (u16*)(ws + 109051904);    // 16 MiB  [8192][1024]
  u16* a1     = (u16*)(ws + 75497472);     // 64 MiB  [8192][4096], reuses qb/kb/attnb

  dim3 blk(256);

  // weights -> bf16, transposed to [N][K]
  transpose_k<<<dim3(32, 2, 16),  blk, 0, stream>>>(Wq, Wqkv_t,            1024, 64);
  transpose_k<<<dim3(32, 2, 16),  blk, 0, stream>>>(Wk, Wqkv_t + 1048576,  1024, 64);
  transpose_k<<<dim3(32, 2, 16),  blk, 0, stream>>>(Wv, Wqkv_t + 2097152,  1024, 64);
  transpose_k<<<dim3(32, 32, 1),  blk, 0, stream>>>(Wo, Wo_t,              1024, 1024);
  transpose_k<<<dim3(32, 128, 1), blk, 0, stream>>>(W1, W1_t,              1024, 4096);
  transpose_k<<<dim3(128, 32, 1), blk, 0, stream>>>(W2, W2_t,              4096, 1024);

  // LN1
  ln_k<<<8192, blk, 0, stream>>>(x, g1, be1, hbuf);
  // QKV projection with fragment-order scatter epilogue (q pre-scaled)
  gemm_k<0><<<dim3(64, 24), blk, 0, stream>>>(hbuf, Wqkv_t, nullptr, nullptr,
                                              qb, kb, vtb, 8192, 3072, 1024);
  // causal flash attention (32 q-rows per wave, 128 per block)
  flash_k<<<dim3(64, 16), blk, 0, stream>>>(qb, kb, vtb, attnb);
  // output projection + bias + residual -> x2 (f32; overwrites dead vtb)
  gemm_k<1><<<dim3(64, 8), blk, 0, stream>>>(attnb, Wo_t, bo, x,
                                             x2, nullptr, nullptr, 8192, 1024, 1024);
  // LN2
  ln_k<<<8192, blk, 0, stream>>>(x2, g2, be2, hbuf);
  // MLP up + relu
  gemm_k<2><<<dim3(64, 32), blk, 0, stream>>>(hbuf, W1_t, b1, nullptr,
                                              a1, nullptr, nullptr, 8192, 4096, 1024);
  // MLP down + bias + residual -> out (f32)
  gemm_k<3><<<dim3(64, 8), blk, 0, stream>>>(a1, W2_t, b2, x2,
                                             out, nullptr, nullptr, 8192, 1024, 4096);
}